// Round 3
// baseline (780.954 us; speedup 1.0000x reference)
//
#include <hip/hip_runtime.h>

#define N_NODES 50000
#define T_STEPS 8
#define C_FEAT  64
#define E_EDGES 800000
#define NBLK_SCAN 49   // ceil(N/1024)
#define DPB 32         // dsts per fused-conv block
#define SPAD 516       // LDS cat row stride (512+4 -> conflict-free col reads)

// ---------------- tiny utility kernels ----------------
__global__ __launch_bounds__(256) void zero_int(int* __restrict__ p, int n) {
    int i = blockIdx.x * 256 + threadIdx.x;
    if (i < n) p[i] = 0;
}

// ---------------- CSR build: hist -> scan -> scatter ----------------
__global__ __launch_bounds__(256) void hist_dst(const int* __restrict__ dst, int* __restrict__ cnt) {
    int e = blockIdx.x * 256 + threadIdx.x;
    if (e < E_EDGES) atomicAdd(&cnt[dst[e]], 1);
}

__global__ __launch_bounds__(1024) void scan1(int* __restrict__ arr, int* __restrict__ bsum) {
    __shared__ int s[1024];
    int i = blockIdx.x * 1024 + threadIdx.x;
    int v = (i < N_NODES) ? arr[i] : 0;
    s[threadIdx.x] = v;
    __syncthreads();
    int acc = v;
    #pragma unroll
    for (int d = 1; d < 1024; d <<= 1) {
        int other = (threadIdx.x >= d) ? s[threadIdx.x - d] : 0;
        __syncthreads();
        acc += other;
        s[threadIdx.x] = acc;
        __syncthreads();
    }
    if (i < N_NODES) arr[i] = acc - v;               // exclusive (local)
    if (threadIdx.x == 1023) bsum[blockIdx.x] = acc; // block total
}

__global__ void scan2(const int* __restrict__ bsum, int* __restrict__ bofs) {
    if (threadIdx.x == 0) {
        int run = 0;
        for (int b = 0; b < NBLK_SCAN; ++b) { bofs[b] = run; run += bsum[b]; }
    }
}

__global__ __launch_bounds__(256) void scan3(int* __restrict__ arr, const int* __restrict__ bofs) {
    int i = blockIdx.x * 256 + threadIdx.x;
    if (i < N_NODES) arr[i] += bofs[i >> 10];
}

// cursor[d] advances from seg start to seg end; afterwards arr[d] == seg end.
__global__ __launch_bounds__(256) void scatter_edges(const int* __restrict__ src,
                                                     const int* __restrict__ dst,
                                                     const int* __restrict__ tix,
                                                     int* __restrict__ cursor,
                                                     int* __restrict__ elist) {
    int e = blockIdx.x * 256 + threadIdx.x;
    if (e >= E_EDGES) return;
    int d = dst[e];
    int pos = atomicAdd(&cursor[d], 1);
    elist[pos] = src[e] | (tix[e] << 16);
}

// ---------------- fused conv: LDS cat tile -> GEMM -> relu ----------------
// H[d] = relu(bias + cat[d] @ W), cat[d][t*64+c] = sum_{e: dst=d,t_e=t} X[src_e][c]
#define ACC_SWITCH(T, V)                                              \
    switch (T) {                                                      \
        case 0: a0 += (V); break; case 1: a1 += (V); break;           \
        case 2: a2 += (V); break; case 3: a3 += (V); break;           \
        case 4: a4 += (V); break; case 5: a5 += (V); break;           \
        case 6: a6 += (V); break; default: a7 += (V);                 \
    }

__global__ __launch_bounds__(256) void fused_conv(const float* __restrict__ X,
                                                  const float* __restrict__ W,     // [512,64]
                                                  const float* __restrict__ bias,  // [64]
                                                  const int* __restrict__ segend,
                                                  const int* __restrict__ elist,
                                                  float* __restrict__ H) {
    __shared__ float scat[DPB][SPAD];
    const int tid = threadIdx.x;
    const int dbase = blockIdx.x * DPB;
    const int wave = tid >> 6;
    const int c = tid & 63;

    // ---- stage 1: per-wave CSR gather-aggregate into LDS (lane = channel) ----
    #pragma unroll
    for (int q = 0; q < 8; ++q) {
        int dl = wave * 8 + q;
        int d = dbase + dl;
        float a0 = 0, a1 = 0, a2 = 0, a3 = 0, a4 = 0, a5 = 0, a6 = 0, a7 = 0;
        if (d < N_NODES) {
            int i  = d ? segend[d - 1] : 0;
            int s1 = segend[d];
            for (; i + 1 < s1; i += 2) {
                int p0 = elist[i];
                int p1 = elist[i + 1];
                float v0 = X[(size_t)(p0 & 0xffff) * 64 + c];
                float v1 = X[(size_t)(p1 & 0xffff) * 64 + c];
                int t0 = __builtin_amdgcn_readfirstlane(p0) >> 16;   // wave-uniform
                int t1 = __builtin_amdgcn_readfirstlane(p1) >> 16;
                ACC_SWITCH(t0, v0)
                ACC_SWITCH(t1, v1)
            }
            if (i < s1) {
                int p0 = elist[i];
                float v0 = X[(size_t)(p0 & 0xffff) * 64 + c];
                int t0 = __builtin_amdgcn_readfirstlane(p0) >> 16;
                ACC_SWITCH(t0, v0)
            }
        }
        scat[dl][0 * 64 + c] = a0;
        scat[dl][1 * 64 + c] = a1;
        scat[dl][2 * 64 + c] = a2;
        scat[dl][3 * 64 + c] = a3;
        scat[dl][4 * 64 + c] = a4;
        scat[dl][5 * 64 + c] = a5;
        scat[dl][6 * 64 + c] = a6;
        scat[dl][7 * 64 + c] = a7;
    }
    __syncthreads();

    // ---- stage 2: [32,512] @ [512,64] + bias, relu ----
    const int r0 = (tid >> 4) * 2;   // 2 rows per thread
    const int j0 = (tid & 15) * 4;   // 4 cols per thread
    float acc[2][4] = {};
    for (int k = 0; k < 512; k += 4) {
        float4 A0 = *(const float4*)&scat[r0][k];
        float4 A1 = *(const float4*)&scat[r0 + 1][k];
        float u0[4] = {A0.x, A0.y, A0.z, A0.w};
        float u1[4] = {A1.x, A1.y, A1.z, A1.w};
        const float* wp = W + (size_t)k * 64 + j0;
        #pragma unroll
        for (int kk = 0; kk < 4; ++kk) {
            float4 w = *(const float4*)(wp + kk * 64);
            acc[0][0] = fmaf(u0[kk], w.x, acc[0][0]);
            acc[0][1] = fmaf(u0[kk], w.y, acc[0][1]);
            acc[0][2] = fmaf(u0[kk], w.z, acc[0][2]);
            acc[0][3] = fmaf(u0[kk], w.w, acc[0][3]);
            acc[1][0] = fmaf(u1[kk], w.x, acc[1][0]);
            acc[1][1] = fmaf(u1[kk], w.y, acc[1][1]);
            acc[1][2] = fmaf(u1[kk], w.z, acc[1][2]);
            acc[1][3] = fmaf(u1[kk], w.w, acc[1][3]);
        }
    }
    float4 b = *(const float4*)(bias + j0);
    #pragma unroll
    for (int i = 0; i < 2; ++i) {
        int node = dbase + r0 + i;
        if (node < N_NODES) {
            float4 r;
            r.x = fmaxf(acc[i][0] + b.x, 0.f);
            r.y = fmaxf(acc[i][1] + b.y, 0.f);
            r.z = fmaxf(acc[i][2] + b.z, 0.f);
            r.w = fmaxf(acc[i][3] + b.w, 0.f);
            *(float4*)(H + (size_t)node * C_FEAT + j0) = r;
        }
    }
}

// ---------------- fused adversary MLP + h1 add ----------------
// out = (relu(h2 @ Wa1 + ba1) @ Wa2 + ba2) + h1
__global__ __launch_bounds__(256) void adv_fused(const float* __restrict__ h2,
                                                 const float* __restrict__ Wa1,  // [64,128]
                                                 const float* __restrict__ ba1,  // [128]
                                                 const float* __restrict__ Wa2,  // [128,64]
                                                 const float* __restrict__ ba2,  // [64]
                                                 const float* __restrict__ h1,
                                                 float* __restrict__ out) {
    __shared__ float sH[64][68];
    __shared__ float sT[64][132];
    const int nbase = blockIdx.x * 64;
    const int tid = threadIdx.x;
    const int j0 = (tid & 15) * 4;
    const int n0 = (tid >> 4) * 4;

    #pragma unroll
    for (int i = 0; i < 4; ++i) {
        int row  = (tid >> 4) + i * 16;
        int col4 = (tid & 15);
        int node = nbase + row;
        float4 v = make_float4(0.f, 0.f, 0.f, 0.f);
        if (node < N_NODES)
            v = *(const float4*)(h2 + (size_t)node * C_FEAT + col4 * 4);
        *(float4*)&sH[row][col4 * 4] = v;
    }
    __syncthreads();

    #pragma unroll
    for (int half = 0; half < 2; ++half) {
        const int j = half * 64 + j0;
        float acc[4][4] = {};
        #pragma unroll 8
        for (int k = 0; k < 64; ++k) {
            float4 w = *(const float4*)(Wa1 + k * 128 + j);
            float a0 = sH[n0 + 0][k];
            float a1 = sH[n0 + 1][k];
            float a2 = sH[n0 + 2][k];
            float a3 = sH[n0 + 3][k];
            acc[0][0] = fmaf(a0, w.x, acc[0][0]); acc[0][1] = fmaf(a0, w.y, acc[0][1]);
            acc[0][2] = fmaf(a0, w.z, acc[0][2]); acc[0][3] = fmaf(a0, w.w, acc[0][3]);
            acc[1][0] = fmaf(a1, w.x, acc[1][0]); acc[1][1] = fmaf(a1, w.y, acc[1][1]);
            acc[1][2] = fmaf(a1, w.z, acc[1][2]); acc[1][3] = fmaf(a1, w.w, acc[1][3]);
            acc[2][0] = fmaf(a2, w.x, acc[2][0]); acc[2][1] = fmaf(a2, w.y, acc[2][1]);
            acc[2][2] = fmaf(a2, w.z, acc[2][2]); acc[2][3] = fmaf(a2, w.w, acc[2][3]);
            acc[3][0] = fmaf(a3, w.x, acc[3][0]); acc[3][1] = fmaf(a3, w.y, acc[3][1]);
            acc[3][2] = fmaf(a3, w.z, acc[3][2]); acc[3][3] = fmaf(a3, w.w, acc[3][3]);
        }
        float4 b1 = *(const float4*)(ba1 + j);
        #pragma unroll
        for (int i = 0; i < 4; ++i) {
            float4 r;
            r.x = fmaxf(acc[i][0] + b1.x, 0.f);
            r.y = fmaxf(acc[i][1] + b1.y, 0.f);
            r.z = fmaxf(acc[i][2] + b1.z, 0.f);
            r.w = fmaxf(acc[i][3] + b1.w, 0.f);
            *(float4*)&sT[n0 + i][j] = r;
        }
    }
    __syncthreads();

    float acc[4][4] = {};
    #pragma unroll 8
    for (int k = 0; k < 128; ++k) {
        float4 w = *(const float4*)(Wa2 + k * 64 + j0);
        float a0 = sT[n0 + 0][k];
        float a1 = sT[n0 + 1][k];
        float a2 = sT[n0 + 2][k];
        float a3 = sT[n0 + 3][k];
        acc[0][0] = fmaf(a0, w.x, acc[0][0]); acc[0][1] = fmaf(a0, w.y, acc[0][1]);
        acc[0][2] = fmaf(a0, w.z, acc[0][2]); acc[0][3] = fmaf(a0, w.w, acc[0][3]);
        acc[1][0] = fmaf(a1, w.x, acc[1][0]); acc[1][1] = fmaf(a1, w.y, acc[1][1]);
        acc[1][2] = fmaf(a1, w.z, acc[1][2]); acc[1][3] = fmaf(a1, w.w, acc[1][3]);
        acc[2][0] = fmaf(a2, w.x, acc[2][0]); acc[2][1] = fmaf(a2, w.y, acc[2][1]);
        acc[2][2] = fmaf(a2, w.z, acc[2][2]); acc[2][3] = fmaf(a2, w.w, acc[2][3]);
        acc[3][0] = fmaf(a3, w.x, acc[3][0]); acc[3][1] = fmaf(a3, w.y, acc[3][1]);
        acc[3][2] = fmaf(a3, w.z, acc[3][2]); acc[3][3] = fmaf(a3, w.w, acc[3][3]);
    }
    float4 b2 = *(const float4*)(ba2 + j0);
    #pragma unroll
    for (int i = 0; i < 4; ++i) {
        int node = nbase + n0 + i;
        if (node < N_NODES) {
            float4 hh = *(const float4*)(h1 + (size_t)node * C_FEAT + j0);
            float4 r;
            r.x = acc[i][0] + b2.x + hh.x;
            r.y = acc[i][1] + b2.y + hh.y;
            r.z = acc[i][2] + b2.z + hh.z;
            r.w = acc[i][3] + b2.w + hh.w;
            *(float4*)(out + (size_t)node * C_FEAT + j0) = r;
        }
    }
}

extern "C" void kernel_launch(void* const* d_in, const int* in_sizes, int n_in,
                              void* d_out, int out_size, void* d_ws, size_t ws_size,
                              hipStream_t stream) {
    const float* x   = (const float*)d_in[0];
    const int*   ei  = (const int*)d_in[1];
    const int*   tix = (const int*)d_in[2];
    const float* Wt1 = (const float*)d_in[3];
    const float* bt1 = (const float*)d_in[4];
    const float* Wt2 = (const float*)d_in[5];
    const float* bt2 = (const float*)d_in[6];
    const float* Wa1 = (const float*)d_in[7];
    const float* ba1 = (const float*)d_in[8];
    const float* Wa2 = (const float*)d_in[9];
    const float* ba2 = (const float*)d_in[10];
    float* out = (float*)d_out;

    const int* src = ei;
    const int* dst = ei + E_EDGES;

    // workspace (~29 MB)
    float* h1   = (float*)d_ws;                       // [N,64] 12.8 MB
    float* h2   = h1 + (size_t)N_NODES * 64;          // [N,64] 12.8 MB
    int*   arr  = (int*)(h2 + (size_t)N_NODES * 64);  // N: cnt -> offsets -> seg-ends
    int*   bsum = arr + N_NODES;                      // 64
    int*   bofs = bsum + 64;                          // 64
    int*   elist = bofs + 64;                         // E packed (src | t<<16)

    const int eBlk = (E_EDGES + 255) / 256;           // 3125
    const int nBlk256 = (N_NODES + 255) / 256;        // 196
    const int cBlk = (N_NODES + DPB - 1) / DPB;       // 1563
    const int aBlk = (N_NODES + 63) / 64;             // 782

    // ---- CSR build by dst (reused for both convs) ----
    zero_int<<<nBlk256, 256, 0, stream>>>(arr, N_NODES);
    hist_dst<<<eBlk, 256, 0, stream>>>(dst, arr);
    scan1<<<NBLK_SCAN, 1024, 0, stream>>>(arr, bsum);
    scan2<<<1, 64, 0, stream>>>(bsum, bofs);
    scan3<<<nBlk256, 256, 0, stream>>>(arr, bofs);
    scatter_edges<<<eBlk, 256, 0, stream>>>(src, dst, tix, arr, elist);

    // ---- conv1: x -> h1 ; conv2: h1 -> h2 ----
    fused_conv<<<cBlk, 256, 0, stream>>>(x,  Wt1, bt1, arr, elist, h1);
    fused_conv<<<cBlk, 256, 0, stream>>>(h1, Wt2, bt2, arr, elist, h2);

    // ---- adversary MLP + residual (third conv == h1) ----
    adv_fused<<<aBlk, 256, 0, stream>>>(h2, Wa1, ba1, Wa2, ba2, h1, out);
}

// Round 4
// 370.853 us; speedup vs baseline: 2.1058x; 2.1058x over previous
//
#include <hip/hip_runtime.h>

#define N_NODES 50000
#define T_STEPS 8
#define C_FEAT  64
#define E_EDGES 800000
#define NBLK_SCAN 49   // ceil(N/1024)
#define DPB 16         // dsts per fused-conv block (3125 blocks exactly)
#define SPADU 520      // ushort stride: 1040 B rows, 16B-aligned, 2-way-bank-free

typedef __attribute__((ext_vector_type(8))) short short8;
typedef __attribute__((ext_vector_type(4))) float f32x4;

__device__ __forceinline__ float bf2f(unsigned short u) {
    union { unsigned int i; float f; } v; v.i = ((unsigned int)u) << 16; return v.f;
}
__device__ __forceinline__ unsigned short f2bf(float f) {
    union { float f; unsigned int i; } v; v.f = f;
    unsigned int r = v.i + 0x7fff + ((v.i >> 16) & 1);   // RNE
    return (unsigned short)(r >> 16);
}

// ---------------- prep: f32 -> bf16 casts ----------------
__global__ __launch_bounds__(256) void cvt_bf16(const float* __restrict__ in,
                                                unsigned short* __restrict__ out, int n) {
    int i = blockIdx.x * 256 + threadIdx.x;
    if (i < n) out[i] = f2bf(in[i]);
}

// W [512][64] f32 -> WT [64][512] bf16
__global__ __launch_bounds__(256) void transpose_w(const float* __restrict__ W,
                                                   unsigned short* __restrict__ WT) {
    int i = blockIdx.x * 256 + threadIdx.x;  // i = n*512 + k
    if (i < 64 * 512) {
        int n = i >> 9, k = i & 511;
        WT[i] = f2bf(W[k * 64 + n]);
    }
}

// ---------------- tiny utility kernels ----------------
__global__ __launch_bounds__(256) void zero_int(int* __restrict__ p, int n) {
    int i = blockIdx.x * 256 + threadIdx.x;
    if (i < n) p[i] = 0;
}

// ---------------- CSR build: hist -> scan -> scatter ----------------
__global__ __launch_bounds__(256) void hist_dst(const int* __restrict__ dst, int* __restrict__ cnt) {
    int e = blockIdx.x * 256 + threadIdx.x;
    if (e < E_EDGES) atomicAdd(&cnt[dst[e]], 1);
}

__global__ __launch_bounds__(1024) void scan1(int* __restrict__ arr, int* __restrict__ bsum) {
    __shared__ int s[1024];
    int i = blockIdx.x * 1024 + threadIdx.x;
    int v = (i < N_NODES) ? arr[i] : 0;
    s[threadIdx.x] = v;
    __syncthreads();
    int acc = v;
    #pragma unroll
    for (int d = 1; d < 1024; d <<= 1) {
        int other = (threadIdx.x >= d) ? s[threadIdx.x - d] : 0;
        __syncthreads();
        acc += other;
        s[threadIdx.x] = acc;
        __syncthreads();
    }
    if (i < N_NODES) arr[i] = acc - v;               // exclusive (local)
    if (threadIdx.x == 1023) bsum[blockIdx.x] = acc; // block total
}

__global__ void scan2(const int* __restrict__ bsum, int* __restrict__ bofs) {
    if (threadIdx.x == 0) {
        int run = 0;
        for (int b = 0; b < NBLK_SCAN; ++b) { bofs[b] = run; run += bsum[b]; }
    }
}

__global__ __launch_bounds__(256) void scan3(int* __restrict__ arr, const int* __restrict__ bofs) {
    int i = blockIdx.x * 256 + threadIdx.x;
    if (i < N_NODES) arr[i] += bofs[i >> 10];
}

// cursor[d] advances from seg start to seg end; afterwards arr[d] == seg end.
__global__ __launch_bounds__(256) void scatter_edges(const int* __restrict__ src,
                                                     const int* __restrict__ dst,
                                                     const int* __restrict__ tix,
                                                     int* __restrict__ cursor,
                                                     int* __restrict__ elist) {
    int e = blockIdx.x * 256 + threadIdx.x;
    if (e >= E_EDGES) return;
    int d = dst[e];
    int pos = atomicAdd(&cursor[d], 1);
    elist[pos] = src[e] | (tix[e] << 16);
}

// ---------------- fused conv: bf16 gather -> LDS cat tile -> MFMA GEMM ----------------
#define ACC_SWITCH(T, V)                                              \
    switch (T) {                                                      \
        case 0: a0 += (V); break; case 1: a1 += (V); break;           \
        case 2: a2 += (V); break; case 3: a3 += (V); break;           \
        case 4: a4 += (V); break; case 5: a5 += (V); break;           \
        case 6: a6 += (V); break; default: a7 += (V);                 \
    }

__global__ __launch_bounds__(256, 6) void fused_conv(const unsigned short* __restrict__ Xb,  // [N,64] bf16
                                                     const unsigned short* __restrict__ WT,  // [64,512] bf16 (W^T)
                                                     const float* __restrict__ bias,         // [64] f32
                                                     const int* __restrict__ segend,
                                                     const int* __restrict__ elist,
                                                     float* __restrict__ H,                  // [N,64] f32
                                                     unsigned short* __restrict__ Hb,        // [N,64] bf16
                                                     int writeHb) {
    __shared__ unsigned short scat[DPB][SPADU];
    const int tid = threadIdx.x;
    const int dbase = blockIdx.x * DPB;
    const int wave = tid >> 6;
    const int c = tid & 63;

    // ---- stage 1: per-wave CSR gather-aggregate (lane = channel), 4 dsts/wave ----
    for (int q = 0; q < 4; ++q) {
        int dl = wave * 4 + q;
        int d = dbase + dl;
        float a0 = 0, a1 = 0, a2 = 0, a3 = 0, a4 = 0, a5 = 0, a6 = 0, a7 = 0;
        int i  = d ? segend[d - 1] : 0;
        int s1 = segend[d];
        for (; i + 3 < s1; i += 4) {
            int p0 = elist[i];
            int p1 = elist[i + 1];
            int p2 = elist[i + 2];
            int p3 = elist[i + 3];
            float v0 = bf2f(Xb[(size_t)(p0 & 0xffff) * 64 + c]);
            float v1 = bf2f(Xb[(size_t)(p1 & 0xffff) * 64 + c]);
            float v2 = bf2f(Xb[(size_t)(p2 & 0xffff) * 64 + c]);
            float v3 = bf2f(Xb[(size_t)(p3 & 0xffff) * 64 + c]);
            int t0 = __builtin_amdgcn_readfirstlane(p0) >> 16;   // wave-uniform
            int t1 = __builtin_amdgcn_readfirstlane(p1) >> 16;
            int t2 = __builtin_amdgcn_readfirstlane(p2) >> 16;
            int t3 = __builtin_amdgcn_readfirstlane(p3) >> 16;
            ACC_SWITCH(t0, v0)
            ACC_SWITCH(t1, v1)
            ACC_SWITCH(t2, v2)
            ACC_SWITCH(t3, v3)
        }
        for (; i < s1; ++i) {
            int p0 = elist[i];
            float v0 = bf2f(Xb[(size_t)(p0 & 0xffff) * 64 + c]);
            int t0 = __builtin_amdgcn_readfirstlane(p0) >> 16;
            ACC_SWITCH(t0, v0)
        }
        scat[dl][0 * 64 + c] = f2bf(a0);
        scat[dl][1 * 64 + c] = f2bf(a1);
        scat[dl][2 * 64 + c] = f2bf(a2);
        scat[dl][3 * 64 + c] = f2bf(a3);
        scat[dl][4 * 64 + c] = f2bf(a4);
        scat[dl][5 * 64 + c] = f2bf(a5);
        scat[dl][6 * 64 + c] = f2bf(a6);
        scat[dl][7 * 64 + c] = f2bf(a7);
    }
    __syncthreads();

    // ---- stage 2: [16,512] @ [512,64] via MFMA 16x16x32 bf16; wave w owns cols w*16.. ----
    // A-frag: lane holds A[m=lane&15][k = quad*8 + j], j=0..7 (verified m118/m120 layout)
    // B-frag: lane holds B[k = quad*8 + j][n=lane&15] <- WT[n][k] rows are contiguous
    // C/D   : col = lane&15, row = quad*4 + reg (verified m89/m91)
    const int m = tid & 15;
    const int quad = (tid & 63) >> 4;
    const int n0 = wave * 16;
    f32x4 acc = {0.f, 0.f, 0.f, 0.f};
    const unsigned short* wrow = WT + (size_t)(n0 + m) * 512;
    #pragma unroll
    for (int kc = 0; kc < 16; ++kc) {
        short8 af = *(const short8*)&scat[m][kc * 32 + quad * 8];
        short8 bf = *(const short8*)(wrow + kc * 32 + quad * 8);
        acc = __builtin_amdgcn_mfma_f32_16x16x32_bf16(af, bf, acc, 0, 0, 0);
    }
    const int col = n0 + m;
    const float bcol = bias[col];
    #pragma unroll
    for (int r = 0; r < 4; ++r) {
        int node = dbase + quad * 4 + r;
        float h = fmaxf(acc[r] + bcol, 0.f);
        H[(size_t)node * 64 + col] = h;
        if (writeHb) Hb[(size_t)node * 64 + col] = f2bf(h);
    }
}

// ---------------- fused adversary MLP + h1 add (f32, unchanged) ----------------
__global__ __launch_bounds__(256) void adv_fused(const float* __restrict__ h2,
                                                 const float* __restrict__ Wa1,  // [64,128]
                                                 const float* __restrict__ ba1,  // [128]
                                                 const float* __restrict__ Wa2,  // [128,64]
                                                 const float* __restrict__ ba2,  // [64]
                                                 const float* __restrict__ h1,
                                                 float* __restrict__ out) {
    __shared__ float sH[64][68];
    __shared__ float sT[64][132];
    const int nbase = blockIdx.x * 64;
    const int tid = threadIdx.x;
    const int j0 = (tid & 15) * 4;
    const int n0 = (tid >> 4) * 4;

    #pragma unroll
    for (int i = 0; i < 4; ++i) {
        int row  = (tid >> 4) + i * 16;
        int col4 = (tid & 15);
        int node = nbase + row;
        float4 v = make_float4(0.f, 0.f, 0.f, 0.f);
        if (node < N_NODES)
            v = *(const float4*)(h2 + (size_t)node * C_FEAT + col4 * 4);
        *(float4*)&sH[row][col4 * 4] = v;
    }
    __syncthreads();

    #pragma unroll
    for (int half = 0; half < 2; ++half) {
        const int j = half * 64 + j0;
        float acc[4][4] = {};
        #pragma unroll 8
        for (int k = 0; k < 64; ++k) {
            float4 w = *(const float4*)(Wa1 + k * 128 + j);
            float a0 = sH[n0 + 0][k];
            float a1 = sH[n0 + 1][k];
            float a2 = sH[n0 + 2][k];
            float a3 = sH[n0 + 3][k];
            acc[0][0] = fmaf(a0, w.x, acc[0][0]); acc[0][1] = fmaf(a0, w.y, acc[0][1]);
            acc[0][2] = fmaf(a0, w.z, acc[0][2]); acc[0][3] = fmaf(a0, w.w, acc[0][3]);
            acc[1][0] = fmaf(a1, w.x, acc[1][0]); acc[1][1] = fmaf(a1, w.y, acc[1][1]);
            acc[1][2] = fmaf(a1, w.z, acc[1][2]); acc[1][3] = fmaf(a1, w.w, acc[1][3]);
            acc[2][0] = fmaf(a2, w.x, acc[2][0]); acc[2][1] = fmaf(a2, w.y, acc[2][1]);
            acc[2][2] = fmaf(a2, w.z, acc[2][2]); acc[2][3] = fmaf(a2, w.w, acc[2][3]);
            acc[3][0] = fmaf(a3, w.x, acc[3][0]); acc[3][1] = fmaf(a3, w.y, acc[3][1]);
            acc[3][2] = fmaf(a3, w.z, acc[3][2]); acc[3][3] = fmaf(a3, w.w, acc[3][3]);
        }
        float4 b1 = *(const float4*)(ba1 + j);
        #pragma unroll
        for (int i = 0; i < 4; ++i) {
            float4 r;
            r.x = fmaxf(acc[i][0] + b1.x, 0.f);
            r.y = fmaxf(acc[i][1] + b1.y, 0.f);
            r.z = fmaxf(acc[i][2] + b1.z, 0.f);
            r.w = fmaxf(acc[i][3] + b1.w, 0.f);
            *(float4*)&sT[n0 + i][j] = r;
        }
    }
    __syncthreads();

    float acc[4][4] = {};
    #pragma unroll 8
    for (int k = 0; k < 128; ++k) {
        float4 w = *(const float4*)(Wa2 + k * 64 + j0);
        float a0 = sT[n0 + 0][k];
        float a1 = sT[n0 + 1][k];
        float a2 = sT[n0 + 2][k];
        float a3 = sT[n0 + 3][k];
        acc[0][0] = fmaf(a0, w.x, acc[0][0]); acc[0][1] = fmaf(a0, w.y, acc[0][1]);
        acc[0][2] = fmaf(a0, w.z, acc[0][2]); acc[0][3] = fmaf(a0, w.w, acc[0][3]);
        acc[1][0] = fmaf(a1, w.x, acc[1][0]); acc[1][1] = fmaf(a1, w.y, acc[1][1]);
        acc[1][2] = fmaf(a1, w.z, acc[1][2]); acc[1][3] = fmaf(a1, w.w, acc[1][3]);
        acc[2][0] = fmaf(a2, w.x, acc[2][0]); acc[2][1] = fmaf(a2, w.y, acc[2][1]);
        acc[2][2] = fmaf(a2, w.z, acc[2][2]); acc[2][3] = fmaf(a2, w.w, acc[2][3]);
        acc[3][0] = fmaf(a3, w.x, acc[3][0]); acc[3][1] = fmaf(a3, w.y, acc[3][1]);
        acc[3][2] = fmaf(a3, w.z, acc[3][2]); acc[3][3] = fmaf(a3, w.w, acc[3][3]);
    }
    float4 b2 = *(const float4*)(ba2 + j0);
    #pragma unroll
    for (int i = 0; i < 4; ++i) {
        int node = nbase + n0 + i;
        if (node < N_NODES) {
            float4 hh = *(const float4*)(h1 + (size_t)node * C_FEAT + j0);
            float4 r;
            r.x = acc[i][0] + b2.x + hh.x;
            r.y = acc[i][1] + b2.y + hh.y;
            r.z = acc[i][2] + b2.z + hh.z;
            r.w = acc[i][3] + b2.w + hh.w;
            *(float4*)(out + (size_t)node * C_FEAT + j0) = r;
        }
    }
}

extern "C" void kernel_launch(void* const* d_in, const int* in_sizes, int n_in,
                              void* d_out, int out_size, void* d_ws, size_t ws_size,
                              hipStream_t stream) {
    const float* x   = (const float*)d_in[0];
    const int*   ei  = (const int*)d_in[1];
    const int*   tix = (const int*)d_in[2];
    const float* Wt1 = (const float*)d_in[3];
    const float* bt1 = (const float*)d_in[4];
    const float* Wt2 = (const float*)d_in[5];
    const float* bt2 = (const float*)d_in[6];
    const float* Wa1 = (const float*)d_in[7];
    const float* ba1 = (const float*)d_in[8];
    const float* Wa2 = (const float*)d_in[9];
    const float* ba2 = (const float*)d_in[10];
    float* out = (float*)d_out;

    const int* src = ei;
    const int* dst = ei + E_EDGES;

    // workspace (~42 MB)
    float* h1            = (float*)d_ws;                        // [N,64] f32
    float* h2            = h1 + (size_t)N_NODES * 64;           // [N,64] f32
    unsigned short* xb   = (unsigned short*)(h2 + (size_t)N_NODES * 64);  // [N,64] bf16
    unsigned short* h1b  = xb + (size_t)N_NODES * 64;           // [N,64] bf16
    unsigned short* WT1  = h1b + (size_t)N_NODES * 64;          // [64,512] bf16
    unsigned short* WT2  = WT1 + 64 * 512;
    int*   arr   = (int*)(WT2 + 64 * 512);                      // N: cnt -> offsets -> seg-ends
    int*   bsum  = arr + N_NODES;                               // 64
    int*   bofs  = bsum + 64;                                   // 64
    int*   elist = bofs + 64;                                   // E packed (src | t<<16)

    const int eBlk = (E_EDGES + 255) / 256;           // 3125
    const int nBlk256 = (N_NODES + 255) / 256;        // 196
    const int cBlk = N_NODES / DPB;                   // 3125 (exact)
    const int aBlk = (N_NODES + 63) / 64;             // 782
    const int xBlk = (N_NODES * 64 + 255) / 256;      // 12500

    // ---- prep: bf16 casts + W transposes ----
    cvt_bf16<<<xBlk, 256, 0, stream>>>(x, xb, N_NODES * 64);
    transpose_w<<<128, 256, 0, stream>>>(Wt1, WT1);
    transpose_w<<<128, 256, 0, stream>>>(Wt2, WT2);

    // ---- CSR build by dst (reused for both convs) ----
    zero_int<<<nBlk256, 256, 0, stream>>>(arr, N_NODES);
    hist_dst<<<eBlk, 256, 0, stream>>>(dst, arr);
    scan1<<<NBLK_SCAN, 1024, 0, stream>>>(arr, bsum);
    scan2<<<1, 64, 0, stream>>>(bsum, bofs);
    scan3<<<nBlk256, 256, 0, stream>>>(arr, bofs);
    scatter_edges<<<eBlk, 256, 0, stream>>>(src, dst, tix, arr, elist);

    // ---- conv1: xb -> h1 (+h1b) ; conv2: h1b -> h2 ----
    fused_conv<<<cBlk, 256, 0, stream>>>(xb,  WT1, bt1, arr, elist, h1, h1b, 1);
    fused_conv<<<cBlk, 256, 0, stream>>>(h1b, WT2, bt2, arr, elist, h2, h1b, 0);

    // ---- adversary MLP + residual (third conv == h1) ----
    adv_fused<<<aBlk, 256, 0, stream>>>(h2, Wa1, ba1, Wa2, ba2, h1, out);
}